// Round 9
// baseline (350.564 us; speedup 1.0000x reference)
//
#include <hip/hip_runtime.h>
#include <cstdint>
#include <cstddef>

#define B_DIM 512
#define T_DIM 200
#define D_DIM 512
#define NPAD  208   // N padded to 13*16
#define NKG   28    // K padded to 224 = 28 groups of 8
#define NT    13    // n-tiles of 16
#define KS_STEPS 7  // 224 / 32
// One 16-col X slice in LDS: [kg 0..24][m 0..15][j 0..7] bf16 = 3200 shorts
// + 8 pad shorts (bank stagger). 4 slices (64 d-cols) x 2 buffers.
#define SLICE 3208

typedef short  short8  __attribute__((ext_vector_type(8)));
typedef float  floatx4 __attribute__((ext_vector_type(4)));

__device__ __forceinline__ float bf2f(unsigned short h) {
  return __uint_as_float(((unsigned int)h) << 16);
}
__device__ __forceinline__ unsigned short f2bf(float f) {
  unsigned int u = __float_as_uint(f);
  u += 0x7fffu + ((u >> 16) & 1u);
  return (unsigned short)(u >> 16);
}
// packed f32x2 -> bf16x2 (RTNE)
__device__ __forceinline__ unsigned int cvt_pk_bf16(float a, float b) {
  unsigned int d;
  asm("v_cvt_pk_bf16_f32 %0, %1, %2" : "=v"(d) : "v"(a), "v"(b));
  return d;
}

// W (200x200 fp32) -> bf16, padded 224x208, B-fragment layout [k/8][n][k%8]
__global__ void prep_w_kernel(const float* __restrict__ W,
                              unsigned short* __restrict__ wf) {
  int idx = blockIdx.x * blockDim.x + threadIdx.x;
  if (idx >= NKG * 8 * NPAD) return;
  int k = idx / NPAD;
  int n = idx - k * NPAD;
  float v = (k < T_DIM && n < T_DIM) ? W[k * T_DIM + n] : 0.0f;
  wf[((size_t)(k >> 3) * NPAD + n) * 8 + (k & 7)] = f2bf(v);
}

// R8 post-mortem: 4 resident blocks/CU run phase-LOCKSTEP (stage together ->
// queue on HBM; compute together; wait together). Delivered HBM ~0.9 TB/s
// with every pipe <40%. R9 breaks the correlation: PERSISTENT blocks (512 x
// 512thr, 8 waves), one batch item each, 8 d-tiles iterated with cross-item
// software pipelining: item n+1's X (7 float4/thread, 28 VGPR) issued
// between K-loop and epilogue (HBM latency hides under epilogue), drained
// into the other LDS buffer after the combine barrier. Only item 0 is cold.
// Phase-wise reg audit keeps total <=128 at (512,4); LDS 59.5 KB.
__global__ __launch_bounds__(512, 4)
void attn_kernel(const float* __restrict__ X,
                 const unsigned short* __restrict__ wf,
                 const float* __restrict__ bias,
                 float* __restrict__ out) {
  __shared__ __align__(16) unsigned short Xa[2][4 * SLICE];
  __shared__ __align__(16) float comb[8][2][64][2];  // [wave][oct][d-col][p,rs]

  const int tid  = threadIdx.x;
  const int wv   = tid >> 6;
  const int lane = tid & 63;
  const int l15  = lane & 15;
  const int g    = lane >> 4;

  const int bb = blockIdx.x;              // one batch item per block

  // staging geometry: 512 threads cover 32 rows x 16 float4 per round;
  // 7 rounds cover t = 0..199 (round 6: t = 192 + t0, needs t0 < 8).
  const int c4 = tid & 15;
  const int t0 = tid >> 4;                // 0..31
  const float* src0 = X + (size_t)bb * (T_DIM * D_DIM)
                      + (size_t)t0 * D_DIM + (c4 << 2);
  // LDS scatter base (buffer-relative, in shorts)
  const int dbase = (c4 >> 2) * SLICE
                  + ((t0 >> 3) * 16 + ((c4 & 3) << 2)) * 8 + (t0 & 7);

  // wave's s-range: waves 0..4 -> 2 n-tiles, waves 5..7 -> 1
  const int nt0 = (wv < 5) ? 2 * wv : (wv + 5);   // 0,2,4,6,8,10,11,12
  const int ntw = (wv < 5) ? 2 : 1;

  // item-independent epilogue constants (t depends only on wave/lane)
  float bb2[2];
  int   xb16[2];
  bool  val[2];
  #pragma unroll
  for (int j = 0; j < 2; ++j) {
    const int t = (nt0 + j) * 16 + l15;
    val[j] = (j < ntw) && (t < T_DIM);
    const int tc = (t < T_DIM) ? t : (T_DIM - 1);
    bb2[j]  = 2.0f * bias[tc];
    xb16[j] = ((tc >> 3) * 16) * 8 + (tc & 7);
  }

  // B-frag lane base into wf
  const unsigned short* wk = wf + ((size_t)g * NPAD + nt0 * 16 + l15) * 8;

  float4 pf[7];
  // ---- prologue: cold-stage item 0 into buffer 0
  #pragma unroll
  for (int it = 0; it < 7; ++it)
    if (it < 6 || tid < 128) pf[it] = *(const float4*)(src0 + (size_t)it * 32 * D_DIM);
  {
    unsigned short* dst = &Xa[0][dbase];
    #pragma unroll
    for (int it = 0; it < 7; ++it) {
      if (it < 6 || tid < 128) {
        unsigned int w01 = cvt_pk_bf16(pf[it].x, pf[it].y);
        unsigned int w23 = cvt_pk_bf16(pf[it].z, pf[it].w);
        dst[0]  = (unsigned short)(w01 & 0xffffu);
        dst[8]  = (unsigned short)(w01 >> 16);
        dst[16] = (unsigned short)(w23 & 0xffffu);
        dst[24] = (unsigned short)(w23 >> 16);
      }
      dst += 512;                         // t += 32 -> 4 rows of [16][8]
    }
  }
  __syncthreads();

  #pragma unroll 2
  for (int n = 0; n < 8; ++n) {
    const int cur = n & 1;
    const unsigned short* Xw = &Xa[cur][0];

    // ---- K-loop on item n (L2 + LDS only)
    floatx4 acc[4][2];
    #pragma unroll
    for (int h = 0; h < 4; ++h)
      #pragma unroll
      for (int j = 0; j < 2; ++j)
        acc[h][j] = (floatx4){0.f, 0.f, 0.f, 0.f};

    #pragma unroll
    for (int ks = 0; ks < KS_STEPS; ++ks) {
      const int kg = ks * 4 + g;
      short8 b0 = *(const short8*)(wk + (size_t)ks * (4 * NPAD * 8));
      short8 b1;
      if (ntw == 2) b1 = *(const short8*)(wk + (size_t)ks * (4 * NPAD * 8) + 128);
      const bool av = (ks < 6) || (g == 0);   // kg 25..27 rows are zero
      short8 a[4];
      #pragma unroll
      for (int h = 0; h < 4; ++h)
        a[h] = av ? *(const short8*)&Xw[h * SLICE + (kg * 16 + l15) * 8]
                  : (short8){0, 0, 0, 0, 0, 0, 0, 0};
      #pragma unroll
      for (int h = 0; h < 4; ++h)
        acc[h][0] = __builtin_amdgcn_mfma_f32_16x16x32_bf16(a[h], b0, acc[h][0], 0, 0, 0);
      if (ntw == 2) {
        #pragma unroll
        for (int h = 0; h < 4; ++h)
          acc[h][1] = __builtin_amdgcn_mfma_f32_16x16x32_bf16(a[h], b1, acc[h][1], 0, 0, 0);
      }
    }

    // ---- issue next item's X loads NOW: latency hides under the epilogue
    if (n < 7) {
      const float* src = src0 + ((n + 1) << 6);
      #pragma unroll
      for (int it = 0; it < 7; ++it)
        if (it < 6 || tid < 128) pf[it] = *(const float4*)(src + (size_t)it * 32 * D_DIM);
    }

    // ---- fused epilogue: p' = exp(-2/(u+1)), u = exp(2z+2b) (softmax
    // scale-invariant, tanh bounded => no max pass).
    // C/D layout: col = l15 (= s in tile), row m = g*4 + r; d = h*16 + m.
    float part[4][4], rs[4][4];
    #pragma unroll
    for (int h = 0; h < 4; ++h)
      #pragma unroll
      for (int r = 0; r < 4; ++r) { part[h][r] = 0.f; rs[h][r] = 0.f; }

    #pragma unroll
    for (int j = 0; j < 2; ++j) {
      if (j < ntw) {
        const unsigned short* xp = &Xw[xb16[j]];
        #pragma unroll
        for (int r = 0; r < 4; ++r) {
          const int m = g * 4 + r;
          #pragma unroll
          for (int h = 0; h < 4; ++h) {
            float u  = __expf(__builtin_fmaf(acc[h][j][r], 2.0f, bb2[j]));
            float v  = __fdividef(2.0f, u + 1.0f);
            float p  = val[j] ? __expf(-v) : 0.0f;
            rs[h][r]   += p;
            part[h][r] += p * bf2f(xp[h * SLICE + m * 8]);
          }
        }
      }
    }
    // 3-round reduce over s-lanes (octs), finish in LDS
    #pragma unroll
    for (int off = 1; off <= 4; off <<= 1)
      #pragma unroll
      for (int h = 0; h < 4; ++h)
        #pragma unroll
        for (int r = 0; r < 4; ++r) {
          part[h][r] += __shfl_xor(part[h][r], off, 16);
          rs[h][r]   += __shfl_xor(rs[h][r],   off, 16);
        }
    if ((l15 & 7) == 0) {
      const int q = l15 >> 3;
      #pragma unroll
      for (int h = 0; h < 4; ++h)
        #pragma unroll
        for (int r = 0; r < 4; ++r) {
          const int idx = h * 16 + g * 4 + r;
          comb[wv][q][idx][0] = part[h][r];
          comb[wv][q][idx][1] = rs[h][r];
        }
    }
    __syncthreads();

    if (tid < 64) {
      float ps = 0.f, ss = 0.f;
      #pragma unroll
      for (int w = 0; w < 8; ++w)
        #pragma unroll
        for (int q = 0; q < 2; ++q) {
          const float2 v = *(const float2*)&comb[w][q][tid][0];
          ps += v.x;
          ss += v.y;
        }
      out[(size_t)bb * D_DIM + (n << 6) + tid] = ps * __frcp_rn(ss);
    }

    // ---- drain prefetch into the other buffer; publish for item n+1
    if (n < 7) {
      unsigned short* dst = &Xa[cur ^ 1][dbase];
      #pragma unroll
      for (int it = 0; it < 7; ++it) {
        if (it < 6 || tid < 128) {
          unsigned int w01 = cvt_pk_bf16(pf[it].x, pf[it].y);
          unsigned int w23 = cvt_pk_bf16(pf[it].z, pf[it].w);
          dst[0]  = (unsigned short)(w01 & 0xffffu);
          dst[8]  = (unsigned short)(w01 >> 16);
          dst[16] = (unsigned short)(w23 & 0xffffu);
          dst[24] = (unsigned short)(w23 >> 16);
        }
        dst += 512;
      }
      __syncthreads();
    }
  }
}

extern "C" void kernel_launch(void* const* d_in, const int* in_sizes, int n_in,
                              void* d_out, int out_size, void* d_ws, size_t ws_size,
                              hipStream_t stream) {
  const float* X  = (const float*)d_in[0];
  const float* W  = (const float*)d_in[1];
  const float* bs = (const float*)d_in[2];
  float* out = (float*)d_out;
  unsigned short* wf = (unsigned short*)d_ws;  // needs 224*208*2 = 93,184 B

  const int wtot = NKG * 8 * NPAD;
  hipLaunchKernelGGL(prep_w_kernel, dim3((wtot + 255) / 256), dim3(256), 0, stream,
                     W, wf);
  // persistent: 512 blocks (2/CU resident), one batch item each, 8 d-tiles
  hipLaunchKernelGGL(attn_kernel, dim3(512), dim3(512), 0, stream,
                     X, wf, bs, out);
}

// Round 10
// 308.910 us; speedup vs baseline: 1.1348x; 1.1348x over previous
//
#include <hip/hip_runtime.h>
#include <cstdint>
#include <cstddef>

#define B_DIM 512
#define T_DIM 200
#define D_DIM 512
#define NPAD  208   // N padded to 13*16
#define NKG   28    // K padded to 224 = 28 groups of 8
#define NT    13    // n-tiles of 16
#define KS_STEPS 7  // 224 / 32
// One 16-col X slice in LDS: [kg 0..24][m 0..15][j 0..7] bf16 = 3200 shorts
// + 8 pad shorts (bank stagger). 4 slices = one 64-col d-tile.
#define SLICE 3208

typedef short  short8  __attribute__((ext_vector_type(8)));
typedef float  floatx4 __attribute__((ext_vector_type(4)));

__device__ __forceinline__ float bf2f(unsigned short h) {
  return __uint_as_float(((unsigned int)h) << 16);
}
__device__ __forceinline__ unsigned short f2bf(float f) {
  unsigned int u = __float_as_uint(f);
  u += 0x7fffu + ((u >> 16) & 1u);
  return (unsigned short)(u >> 16);
}
// packed f32x2 -> bf16x2 (RTNE)
__device__ __forceinline__ unsigned int cvt_pk_bf16(float a, float b) {
  unsigned int d;
  asm("v_cvt_pk_bf16_f32 %0, %1, %2" : "=v"(d) : "v"(a), "v"(b));
  return d;
}

// W (200x200 fp32) -> bf16, padded 224x208, B-fragment layout [k/8][n][k%8]
__global__ void prep_w_kernel(const float* __restrict__ W,
                              unsigned short* __restrict__ wf) {
  int idx = blockIdx.x * blockDim.x + threadIdx.x;
  if (idx >= NKG * 8 * NPAD) return;
  int k = idx / NPAD;
  int n = idx - k * NPAD;
  float v = (k < T_DIM && n < T_DIM) ? W[k * T_DIM + n] : 0.0f;
  wf[((size_t)(k >> 3) * NPAD + n) * 8 + (k & 7)] = f2bf(v);
}

// R9 post-mortem: pf[7] held across epilogue blew the 128-reg union ->
// spills (WRITE 68 MB). R10 eliminates the K-loop's global traffic
// entirely instead of hiding it: PERSISTENT blocks (512 x 512thr), each
// owns one batch item, iterates 8 d-tiles; W B-FRAGMENTS LIVE IN
// REGISTERS FOR THE WHOLE KERNEL (heavy wave: bA[7]+bB[7] = 56 regs,
// loaded once, reused 8x). K-loop = pure LDS + MFMA, zero global loads.
// nt-split {2x5, 1x3} over 8 waves; epilogue processed per-h so part/rs
// is 8 regs not 32. Phase-wise live sets: stage ~95, K ~110, epi ~105 --
// all < 128 at (512,4). Global traffic: X once + wf once/block + out.
__global__ __launch_bounds__(512, 4)
void attn_kernel(const float* __restrict__ X,
                 const unsigned short* __restrict__ wf,
                 const float* __restrict__ bias,
                 float* __restrict__ out) {
  __shared__ __align__(16) unsigned short Xs[4 * SLICE];       // 25,664 B
  __shared__ __align__(16) float comb[8][2][64][2];            //  8,192 B

  const int tid  = threadIdx.x;
  const int wv   = tid >> 6;
  const int lane = tid & 63;
  const int l15  = lane & 15;
  const int g    = lane >> 4;

  const int bb = blockIdx.x;              // one batch item per block

  // wave's s-range: waves 0..4 -> 2 n-tiles, waves 5..7 -> 1
  const int nt0 = (wv < 5) ? 2 * wv : (wv + 5);   // 0,2,4,6,8,10,11,12
  const int ntw = (wv < 5) ? 2 : 1;

  // item-independent epilogue constants
  float bb2[2];
  int   xb16[2];
  bool  val[2];
  #pragma unroll
  for (int j = 0; j < 2; ++j) {
    const int t = (nt0 + j) * 16 + l15;
    val[j] = (t < T_DIM);                 // only fails on nt==12, l15>=8
    const int tc = (t < T_DIM) ? t : (T_DIM - 1);
    bb2[j]  = 2.0f * bias[tc];
    xb16[j] = ((tc >> 3) * 16) * 8 + (tc & 7);
  }

  // ---- persistent B-frags: loaded ONCE, live for the whole kernel.
  const unsigned short* wk = wf + ((size_t)g * NPAD + nt0 * 16 + l15) * 8;
  short8 bA[7], bB[7];
  #pragma unroll
  for (int ks = 0; ks < KS_STEPS; ++ks) {
    bA[ks] = *(const short8*)(wk + (size_t)ks * (4 * NPAD * 8));
    if (ntw == 2)
      bB[ks] = *(const short8*)(wk + (size_t)ks * (4 * NPAD * 8) + 128);
  }

  // staging geometry: 512 threads cover 32 rows x 16 float4 per round;
  // 7 rounds cover t = 0..199 (round 6 active for tid < 128).
  const int c4 = tid & 15;
  const int t0 = tid >> 4;                // 0..31
  const float* srcb = X + (size_t)bb * (T_DIM * D_DIM)
                      + (size_t)t0 * D_DIM + (c4 << 2);
  const int dbase = (c4 >> 2) * SLICE
                  + ((t0 >> 3) * 16 + ((c4 & 3) << 2)) * 8 + (t0 & 7);

  #pragma unroll 1
  for (int n = 0; n < 8; ++n) {
    // ---- stage d-tile n (issue all 7 loads, then convert+scatter)
    {
      const float* src = srcb + (n << 6);
      float4 pf[7];
      #pragma unroll
      for (int it = 0; it < 7; ++it)
        if (it < 6 || tid < 128)
          pf[it] = *(const float4*)(src + (size_t)it * 32 * D_DIM);
      unsigned short* dst = &Xs[dbase];
      #pragma unroll
      for (int it = 0; it < 7; ++it) {
        if (it < 6 || tid < 128) {
          unsigned int w01 = cvt_pk_bf16(pf[it].x, pf[it].y);
          unsigned int w23 = cvt_pk_bf16(pf[it].z, pf[it].w);
          dst[0]  = (unsigned short)(w01 & 0xffffu);
          dst[8]  = (unsigned short)(w01 >> 16);
          dst[16] = (unsigned short)(w23 & 0xffffu);
          dst[24] = (unsigned short)(w23 >> 16);
        }
        dst += 512;                       // t += 32
      }
    }
    __syncthreads();

    // ---- K-loop: pure LDS + MFMA (B-frags already in registers)
    floatx4 acc[4][2];
    #pragma unroll
    for (int h = 0; h < 4; ++h)
      #pragma unroll
      for (int j = 0; j < 2; ++j)
        acc[h][j] = (floatx4){0.f, 0.f, 0.f, 0.f};

    __builtin_amdgcn_s_setprio(1);
    #pragma unroll
    for (int ks = 0; ks < KS_STEPS; ++ks) {
      const int kg = ks * 4 + g;
      const bool av = (ks < 6) || (g == 0);   // kg 25..27 rows are zero
      short8 a[4];
      #pragma unroll
      for (int h = 0; h < 4; ++h)
        a[h] = av ? *(const short8*)&Xs[h * SLICE + (kg * 16 + l15) * 8]
                  : (short8){0, 0, 0, 0, 0, 0, 0, 0};
      #pragma unroll
      for (int h = 0; h < 4; ++h)
        acc[h][0] = __builtin_amdgcn_mfma_f32_16x16x32_bf16(a[h], bA[ks], acc[h][0], 0, 0, 0);
      if (ntw == 2) {
        #pragma unroll
        for (int h = 0; h < 4; ++h)
          acc[h][1] = __builtin_amdgcn_mfma_f32_16x16x32_bf16(a[h], bB[ks], acc[h][1], 0, 0, 0);
      }
    }
    __builtin_amdgcn_s_setprio(0);

    // ---- fused epilogue, one d-slice h at a time (part/rs = 8 regs):
    // p' = exp(-2/(u+1)), u = exp(2z+2b) (softmax scale-invariance;
    // tanh bounded => no max pass).
    // C/D layout: col = l15 (= s in tile), row m = g*4 + r.
    #pragma unroll
    for (int h = 0; h < 4; ++h) {
      float part[4] = {0.f, 0.f, 0.f, 0.f};
      float rs[4]   = {0.f, 0.f, 0.f, 0.f};
      #pragma unroll
      for (int j = 0; j < 2; ++j) {
        if (j < ntw) {
          const unsigned short* xp = &Xs[h * SLICE + xb16[j]];
          #pragma unroll
          for (int r = 0; r < 4; ++r) {
            float u = __expf(__builtin_fmaf(acc[h][j][r], 2.0f, bb2[j]));
            float v = __fdividef(2.0f, u + 1.0f);
            float p = val[j] ? __expf(-v) : 0.0f;
            rs[r]   += p;
            part[r] += p * bf2f(xp[(g * 4 + r) * 8]);   // X[t][d]
          }
        }
      }
      #pragma unroll
      for (int off = 1; off <= 4; off <<= 1)
        #pragma unroll
        for (int r = 0; r < 4; ++r) {
          part[r] += __shfl_xor(part[r], off, 16);
          rs[r]   += __shfl_xor(rs[r],   off, 16);
        }
      if ((l15 & 7) == 0) {
        const int q = l15 >> 3;
        #pragma unroll
        for (int r = 0; r < 4; ++r) {
          const int idx = h * 16 + g * 4 + r;
          comb[wv][q][idx][0] = part[r];
          comb[wv][q][idx][1] = rs[r];
        }
      }
    }
    __syncthreads();

    if (tid < 64) {
      float ps = 0.f, ss = 0.f;
      #pragma unroll
      for (int w = 0; w < 8; ++w)
        #pragma unroll
        for (int q = 0; q < 2; ++q) {
          const float2 v = *(const float2*)&comb[w][q][tid][0];
          ps += v.x;
          ss += v.y;
        }
      out[(size_t)bb * D_DIM + (n << 6) + tid] = ps * __frcp_rn(ss);
    }
    // No third barrier needed: all Xs reads precede bar#2; stage(n+1)
    // writes follow it. comb reads (combine) precede bar#1(n+1); comb
    // writes of iter n+1 follow it.
  }
}

extern "C" void kernel_launch(void* const* d_in, const int* in_sizes, int n_in,
                              void* d_out, int out_size, void* d_ws, size_t ws_size,
                              hipStream_t stream) {
  const float* X  = (const float*)d_in[0];
  const float* W  = (const float*)d_in[1];
  const float* bs = (const float*)d_in[2];
  float* out = (float*)d_out;
  unsigned short* wf = (unsigned short*)d_ws;  // needs 224*208*2 = 93,184 B

  const int wtot = NKG * 8 * NPAD;
  hipLaunchKernelGGL(prep_w_kernel, dim3((wtot + 255) / 256), dim3(256), 0, stream,
                     W, wf);
  // persistent: 512 blocks (2/CU), one batch item each, 8 d-tiles of 64
  hipLaunchKernelGGL(attn_kernel, dim3(512), dim3(512), 0, stream,
                     X, wf, bs, out);
}